// Round 5
// baseline (1245.183 us; speedup 1.0000x reference)
//
#include <hip/hip_runtime.h>
#include <math.h>

// GCN 2-layer, coarse-bucket binning + LDS-accumulator aggregation.
//   R4 profile: full CSR fill = scattered 4B stores -> 194MB HBM write-through
//   (16x line amplification), 280us. Fix: bin edges only by 128-node bucket
//   (782 buckets); aggregate per-bucket into LDS acc with ds_add; one coalesced
//   store per node. Edge packed in 4B: (col&127)<<17 | row (row<2^17).
//   agg[c] = dinv[c]*(sum hs[src] + hs[c]), hs[i]=dinv[i]*(h[i]@W).
// edge_index: int32 (harness-converted; R2 crash proved 8E-byte buffer).
#define F_IN  128
#define F_HID 16
#define F_OUT 32
#define BSH   7            // 128 nodes per bucket
#define BNODES 128
#define MAXBK 1024         // LDS array cap (nbk = 782 for N=100k)
#define CEDGE 4096         // edges per binning chunk (256 thr x 16)

__global__ void k_zero_i(int* p, int n) {
    int i = blockIdx.x * blockDim.x + threadIdx.x;
    if (i < n) p[i] = 0;
}

// per-chunk LDS histogram of bucket ids -> global bucket counts
__global__ void k_bucket_cnt(const int* __restrict__ col, int E,
                             int* __restrict__ bcnt, int nbk) {
    __shared__ int h[MAXBK];
    int t = threadIdx.x;
    for (int k = t; k < nbk; k += 256) h[k] = 0;
    __syncthreads();
    int e0 = blockIdx.x * CEDGE;
#pragma unroll
    for (int k = 0; k < 16; ++k) {
        int e = e0 + k * 256 + t;
        if (e < E) atomicAdd(&h[col[e] >> BSH], 1);
    }
    __syncthreads();
    for (int k = t; k < nbk; k += 256) if (h[k]) atomicAdd(&bcnt[k], h[k]);
}

// single-block exclusive scan of bcnt[nbk] -> bptr, bcur (nbk <= 1024)
__global__ void k_bscan(const int* __restrict__ bcnt, int* __restrict__ bptr,
                        int* __restrict__ bcur, int nbk, int E) {
    __shared__ int sd[256];
    int t = threadIdx.x;
    int base = t * 4;
    int v[4], ts = 0;
#pragma unroll
    for (int k = 0; k < 4; ++k) { v[k] = (base + k < nbk) ? bcnt[base + k] : 0; ts += v[k]; }
    sd[t] = ts;
    __syncthreads();
    for (int off = 1; off < 256; off <<= 1) {
        int x = (t >= off) ? sd[t - off] : 0;
        __syncthreads();
        sd[t] += x;
        __syncthreads();
    }
    int run = sd[t] - ts;
#pragma unroll
    for (int k = 0; k < 4; ++k) {
        if (base + k < nbk) { bptr[base + k] = run; bcur[base + k] = run; }
        run += v[k];
    }
    if (t == 0) bptr[nbk] = E;
}

// bin edges: LDS rank within chunk -> one global reservation per bucket ->
// 4B packed stores near per-bucket cursors (L2-local window).
__global__ void k_bin_fill(const int* __restrict__ row, const int* __restrict__ col,
                           int E, int* __restrict__ bcur, unsigned* __restrict__ pairs) {
    __shared__ int h[MAXBK];
    __shared__ int base[MAXBK];
    int t = threadIdx.x;
    int nbk = (gridDim.y == 1) ? MAXBK : MAXBK;  // nbk passed via loop bound below
    for (int k = t; k < MAXBK; k += 256) h[k] = 0;
    __syncthreads();
    int e0 = blockIdx.x * CEDGE;
    int myb[16], myp[16]; unsigned myv[16];
#pragma unroll
    for (int k = 0; k < 16; ++k) {
        int e = e0 + k * 256 + t;
        myb[k] = -1;
        if (e < E) {
            int c = col[e], r = row[e];
            int b = c >> BSH;
            myb[k] = b;
            myp[k] = atomicAdd(&h[b], 1);
            myv[k] = ((unsigned)(c & (BNODES - 1)) << 17) | (unsigned)r;
        }
    }
    __syncthreads();
    for (int k = t; k < MAXBK; k += 256)
        base[k] = h[k] ? atomicAdd(&bcur[k], h[k]) : 0;
    __syncthreads();
#pragma unroll
    for (int k = 0; k < 16; ++k)
        if (myb[k] >= 0) pairs[base[myb[k]] + myp[k]] = myv[k];
    (void)nbk;
}

// per-bucket in-degree from binned pairs -> dinv (rsqrt(deg+1))
__global__ void k_dinv_bucket(const unsigned* __restrict__ pairs,
                              const int* __restrict__ bptr,
                              float* __restrict__ dinv, int N) {
    __shared__ int c[BNODES];
    int b = blockIdx.x, t = threadIdx.x;
    if (t < BNODES) c[t] = 0;
    __syncthreads();
    int s0 = bptr[b], s1 = bptr[b + 1];
    for (int e = s0 + t; e < s1; e += 256) atomicAdd(&c[pairs[e] >> 17], 1);
    __syncthreads();
    int n = (b << BSH) + t;
    if (t < BNODES && n < N) dinv[n] = rsqrtf((float)c[t] + 1.0f);
}

// 16 nodes x 16 out-ch per 256-thread block. x tile + W1 staged in LDS.
__global__ void k_gemm1(const float* __restrict__ x, const float* __restrict__ W1,
                        const float* __restrict__ dinv, float* __restrict__ hs1, int N) {
    __shared__ float sW[F_IN * F_HID];
    __shared__ float sX[16][F_IN + 1];
    int t = threadIdx.x;
    for (int k = t; k < F_IN * F_HID; k += 256) sW[k] = W1[k];
    int node0 = blockIdx.x * 16;
    for (int k = t; k < 16 * F_IN; k += 256) {
        int r = k / F_IN, c = k % F_IN;
        int n = node0 + r;
        sX[r][c] = (n < N) ? x[(size_t)node0 * F_IN + k] : 0.f;
    }
    __syncthreads();
    int il = t >> 4, j = t & 15;
    float acc = 0.f;
    const float* xr = sX[il];
#pragma unroll 8
    for (int k = 0; k < F_IN; ++k) acc += xr[k] * sW[k * F_HID + j];
    int n = node0 + il;
    if (n < N) hs1[(size_t)n * F_HID + j] = acc * dinv[n];
}

// bucket aggregation layer 1: LDS acc[128][16], 16 lanes/edge, 4-way ILP,
// fused self-loop + dinv + bias + relu epilogue.
__global__ void k_agg1(const float* __restrict__ hs1, const unsigned* __restrict__ pairs,
                       const int* __restrict__ bptr, const float* __restrict__ dinv,
                       const float* __restrict__ b1, float* __restrict__ h1, int N) {
    __shared__ float acc[BNODES * F_HID];
    int t = threadIdx.x;
    for (int k = t; k < BNODES * F_HID; k += 256) acc[k] = 0.f;
    __syncthreads();
    int b = blockIdx.x;
    int s0 = bptr[b], s1 = bptr[b + 1];
    int g = t >> 4, j = t & 15;
    int e = s0;
    for (; e + 64 <= s1; e += 64) {
        unsigned v0 = pairs[e + g];
        unsigned v1 = pairs[e + 16 + g];
        unsigned v2 = pairs[e + 32 + g];
        unsigned v3 = pairs[e + 48 + g];
        float f0 = hs1[(size_t)(v0 & 0x1FFFFu) * F_HID + j];
        float f1 = hs1[(size_t)(v1 & 0x1FFFFu) * F_HID + j];
        float f2 = hs1[(size_t)(v2 & 0x1FFFFu) * F_HID + j];
        float f3 = hs1[(size_t)(v3 & 0x1FFFFu) * F_HID + j];
        atomicAdd(&acc[(v0 >> 17) * F_HID + j], f0);
        atomicAdd(&acc[(v1 >> 17) * F_HID + j], f1);
        atomicAdd(&acc[(v2 >> 17) * F_HID + j], f2);
        atomicAdd(&acc[(v3 >> 17) * F_HID + j], f3);
    }
    for (e += g; e < s1; e += 16) {
        unsigned v = pairs[e];
        atomicAdd(&acc[(v >> 17) * F_HID + j], hs1[(size_t)(v & 0x1FFFFu) * F_HID + j]);
    }
    __syncthreads();
    int n0 = b << BSH;
    for (int k = t; k < BNODES * F_HID; k += 256) {
        int nl = k >> 4, jj = k & 15;
        int n = n0 + nl;
        if (n < N) {
            float v = dinv[n] * (acc[k] + hs1[(size_t)n * F_HID + jj]) + b1[jj];
            h1[(size_t)n * F_HID + jj] = v > 0.f ? v : 0.f;
        }
    }
}

// 8 nodes x 32 out-ch per 256-thread block.
__global__ void k_gemm2(const float* __restrict__ h1, const float* __restrict__ W2,
                        const float* __restrict__ dinv, float* __restrict__ hs2, int N) {
    __shared__ float sW[F_HID * F_OUT];
    __shared__ float sH[8 * F_HID];
    int t = threadIdx.x;
    for (int k = t; k < F_HID * F_OUT; k += 256) sW[k] = W2[k];
    int node0 = blockIdx.x * 8;
    if (t < 8 * F_HID) {
        int n = node0 + t / F_HID;
        sH[t] = (n < N) ? h1[(size_t)node0 * F_HID + t] : 0.f;
    }
    __syncthreads();
    int il = t >> 5, j = t & 31;
    float acc = 0.f;
#pragma unroll
    for (int k = 0; k < F_HID; ++k) acc += sH[il * F_HID + k] * sW[k * F_OUT + j];
    int n = node0 + il;
    if (n < N) hs2[(size_t)n * F_OUT + j] = acc * dinv[n];
}

// bucket aggregation layer 2 + fused bias + log_softmax epilogue.
__global__ void k_agg2_final(const float* __restrict__ hs2, const unsigned* __restrict__ pairs,
                             const int* __restrict__ bptr, const float* __restrict__ dinv,
                             const float* __restrict__ b2, float* __restrict__ out, int N) {
    __shared__ float acc[BNODES * F_OUT];
    int t = threadIdx.x;
    for (int k = t; k < BNODES * F_OUT; k += 256) acc[k] = 0.f;
    __syncthreads();
    int b = blockIdx.x;
    int s0 = bptr[b], s1 = bptr[b + 1];
    int g = t >> 5, j = t & 31;
    int e = s0;
    for (; e + 32 <= s1; e += 32) {
        unsigned v0 = pairs[e + g];
        unsigned v1 = pairs[e + 8 + g];
        unsigned v2 = pairs[e + 16 + g];
        unsigned v3 = pairs[e + 24 + g];
        float f0 = hs2[(size_t)(v0 & 0x1FFFFu) * F_OUT + j];
        float f1 = hs2[(size_t)(v1 & 0x1FFFFu) * F_OUT + j];
        float f2 = hs2[(size_t)(v2 & 0x1FFFFu) * F_OUT + j];
        float f3 = hs2[(size_t)(v3 & 0x1FFFFu) * F_OUT + j];
        atomicAdd(&acc[(v0 >> 17) * F_OUT + j], f0);
        atomicAdd(&acc[(v1 >> 17) * F_OUT + j], f1);
        atomicAdd(&acc[(v2 >> 17) * F_OUT + j], f2);
        atomicAdd(&acc[(v3 >> 17) * F_OUT + j], f3);
    }
    for (e += g; e < s1; e += 8) {
        unsigned v = pairs[e];
        atomicAdd(&acc[(v >> 17) * F_OUT + j], hs2[(size_t)(v & 0x1FFFFu) * F_OUT + j]);
    }
    __syncthreads();
    int n0 = b << BSH;
    for (int nl = g; nl < BNODES; nl += 8) {
        int n = n0 + nl;
        if (n < N) {
            float v = dinv[n] * (acc[nl * F_OUT + j] + hs2[(size_t)n * F_OUT + j]) + b2[j];
            float m = v;
            for (int off = 16; off > 0; off >>= 1) m = fmaxf(m, __shfl_xor(m, off, 32));
            float s = __expf(v - m);
            for (int off = 16; off > 0; off >>= 1) s += __shfl_xor(s, off, 32);
            out[(size_t)n * F_OUT + j] = v - m - __logf(s);
        }
    }
}

extern "C" void kernel_launch(void* const* d_in, const int* in_sizes, int n_in,
                              void* d_out, int out_size, void* d_ws, size_t ws_size,
                              hipStream_t stream) {
    const float* x  = (const float*)d_in[0];
    const int*   ei = (const int*)d_in[1];   // [2, E] int32
    const float* W1 = (const float*)d_in[2];
    const float* b1 = (const float*)d_in[3];
    const float* W2 = (const float*)d_in[4];
    const float* b2 = (const float*)d_in[5];
    float* out = (float*)d_out;

    int N = in_sizes[0] / F_IN;
    int E = in_sizes[1] / 2;
    const int* row = ei;
    const int* col = ei + E;
    int nbk = (N + BNODES - 1) >> BSH;          // 782
    int nchunk = (E + CEDGE - 1) / CEDGE;        // 782

    // ws: dinv[N]f | bcnt[1024]i | bptr[1025]i | bcur[1024]i | pairs[E]u32 |
    //     hs1[16N]f | h1[16N]f | hs2[32N]f   (~39 MB)
    char* w = (char*)d_ws;
    float*    dinv  = (float*)w;     w += sizeof(float) * N;
    int*      bcnt  = (int*)w;       w += sizeof(int) * MAXBK;
    int*      bptr  = (int*)w;       w += sizeof(int) * (MAXBK + 1);
    int*      bcur  = (int*)w;       w += sizeof(int) * MAXBK;
    unsigned* pairs = (unsigned*)w;  w += sizeof(unsigned) * (size_t)E;
    float*    hs1   = (float*)w;     w += sizeof(float) * (size_t)N * F_HID;
    float*    h1    = (float*)w;     w += sizeof(float) * (size_t)N * F_HID;
    float*    hs2   = (float*)w;

    k_zero_i<<<(MAXBK + 255) / 256, 256, 0, stream>>>(bcnt, MAXBK);
    k_bucket_cnt<<<nchunk, 256, 0, stream>>>(col, E, bcnt, nbk);
    k_bscan<<<1, 256, 0, stream>>>(bcnt, bptr, bcur, nbk, E);
    k_bin_fill<<<nchunk, 256, 0, stream>>>(row, col, E, bcur, pairs);
    k_dinv_bucket<<<nbk, 256, 0, stream>>>(pairs, bptr, dinv, N);

    k_gemm1<<<(N + 15) / 16, 256, 0, stream>>>(x, W1, dinv, hs1, N);
    k_agg1<<<nbk, 256, 0, stream>>>(hs1, pairs, bptr, dinv, b1, h1, N);

    k_gemm2<<<(N + 7) / 8, 256, 0, stream>>>(h1, W2, dinv, hs2, N);
    k_agg2_final<<<nbk, 256, 0, stream>>>(hs2, pairs, bptr, dinv, b2, out, N);
}

// Round 6
// 820.842 us; speedup vs baseline: 1.5170x; 1.5170x over previous
//
#include <hip/hip_runtime.h>
#include <math.h>

// GCN 2-layer, 32-node-bucket binning + LDS accumulation, bf16 gather sources,
// W2 commuted past aggregation:  Â(H W2) = (Â H) W2  -> both layers aggregate
// 16 channels (32 B/edge bf16, 3.2 MB source array = per-XCD-L2 resident).
//   hs1 = dinv*(x@W1) [bf16];  h1s = dinv*relu(dinv*(Σ hs1 + self) + b1) [bf16]
//   pre = dinv*(Σ h1s + self);  out = log_softmax(pre@W2 + b2)
// R5 lesson: 782-block grid + fp32 rows = latency-bound (25% occ, 287MB L2 miss).
// edge_index: int32 (harness-converted; R2 crash proved 8E-byte buffer).
#define F_IN  128
#define F_HID 16
#define F_OUT 32
#define BSH    5
#define BNODES 32
#define MAXBK  3328        // 256*13 >= nbk (3125 for N=100k)
#define SCAN_IT 13
#define CEDGE  4096        // edges per binning chunk (256 thr x 16)

typedef unsigned int u32;

__device__ inline float bflo(u32 d) { return __uint_as_float(d << 16); }
__device__ inline float bfhi(u32 d) { return __uint_as_float(d & 0xFFFF0000u); }
__device__ inline u32 f2bf(float f) {
    u32 u = __float_as_uint(f);
    return (u + 0x7FFFu + ((u >> 16) & 1u)) >> 16;  // RNE
}
__device__ inline u32 pk2(float lo, float hi) { return f2bf(lo) | (f2bf(hi) << 16); }

__global__ void k_zero_i(int* p, int n) {
    int i = blockIdx.x * blockDim.x + threadIdx.x;
    if (i < n) p[i] = 0;
}

// per-chunk LDS histogram of bucket ids -> global bucket counts
__global__ void k_bucket_cnt(const int* __restrict__ col, int E,
                             int* __restrict__ bcnt, int nbk) {
    __shared__ int h[MAXBK];
    int t = threadIdx.x;
    for (int k = t; k < nbk; k += 256) h[k] = 0;
    __syncthreads();
    int e0 = blockIdx.x * CEDGE;
#pragma unroll
    for (int k = 0; k < 16; ++k) {
        int e = e0 + k * 256 + t;
        if (e < E) atomicAdd(&h[col[e] >> BSH], 1);
    }
    __syncthreads();
    for (int k = t; k < nbk; k += 256) if (h[k]) atomicAdd(&bcnt[k], h[k]);
}

// single-block exclusive scan of bcnt[nbk] -> bptr, bcur
__global__ void k_bscan(const int* __restrict__ bcnt, int* __restrict__ bptr,
                        int* __restrict__ bcur, int nbk, int E) {
    __shared__ int sd[256];
    int t = threadIdx.x;
    int base = t * SCAN_IT;
    int v[SCAN_IT], ts = 0;
#pragma unroll
    for (int k = 0; k < SCAN_IT; ++k) {
        v[k] = (base + k < nbk) ? bcnt[base + k] : 0;
        ts += v[k];
    }
    sd[t] = ts;
    __syncthreads();
    for (int off = 1; off < 256; off <<= 1) {
        int x = (t >= off) ? sd[t - off] : 0;
        __syncthreads();
        sd[t] += x;
        __syncthreads();
    }
    int run = sd[t] - ts;
#pragma unroll
    for (int k = 0; k < SCAN_IT; ++k) {
        if (base + k < nbk) { bptr[base + k] = run; bcur[base + k] = run; }
        run += v[k];
    }
    if (t == 0) bptr[nbk] = E;
}

// bin edges by bucket: LDS rank in chunk -> one global reservation per bucket
// -> packed 4B stores near per-bucket cursors.  pack = (col&31)<<17 | row.
__global__ void k_bin_fill(const int* __restrict__ row, const int* __restrict__ col,
                           int E, int* __restrict__ bcur, u32* __restrict__ pairs,
                           int nbk) {
    __shared__ int h[MAXBK];
    __shared__ int bse[MAXBK];
    int t = threadIdx.x;
    for (int k = t; k < nbk; k += 256) h[k] = 0;
    __syncthreads();
    int e0 = blockIdx.x * CEDGE;
    int myb[16], myp[16]; u32 myv[16];
#pragma unroll
    for (int k = 0; k < 16; ++k) {
        int e = e0 + k * 256 + t;
        myb[k] = -1;
        if (e < E) {
            int c = col[e], r = row[e];
            int b = c >> BSH;
            myb[k] = b;
            myp[k] = atomicAdd(&h[b], 1);
            myv[k] = ((u32)(c & (BNODES - 1)) << 17) | (u32)r;
        }
    }
    __syncthreads();
    for (int k = t; k < nbk; k += 256)
        bse[k] = h[k] ? atomicAdd(&bcur[k], h[k]) : 0;
    __syncthreads();
#pragma unroll
    for (int k = 0; k < 16; ++k)
        if (myb[k] >= 0) pairs[bse[myb[k]] + myp[k]] = myv[k];
}

// per-bucket in-degree -> dinv = rsqrt(deg+1)
__global__ void k_dinv_bucket(const u32* __restrict__ pairs, const int* __restrict__ bptr,
                              float* __restrict__ dinv, int N) {
    __shared__ int c[BNODES];
    int b = blockIdx.x, t = threadIdx.x;
    if (t < BNODES) c[t] = 0;
    __syncthreads();
    int s0 = bptr[b], s1 = bptr[b + 1];
    for (int e = s0 + t; e < s1; e += 256) atomicAdd(&c[pairs[e] >> 17], 1);
    __syncthreads();
    int n = (b << BSH) + t;
    if (t < BNODES && n < N) dinv[n] = rsqrtf((float)c[t] + 1.0f);
}

// 16 nodes x 16 ch per block; output bf16-packed hs1 = dinv*(x@W1).
__global__ void k_gemm1(const float* __restrict__ x, const float* __restrict__ W1,
                        const float* __restrict__ dinv, u32* __restrict__ hs1b, int N) {
    __shared__ float sW[F_IN * F_HID];
    __shared__ float sX[16][F_IN + 1];
    int t = threadIdx.x;
    for (int k = t; k < F_IN * F_HID; k += 256) sW[k] = W1[k];
    int node0 = blockIdx.x * 16;
    for (int k = t; k < 16 * F_IN; k += 256) {
        int r = k / F_IN, c = k % F_IN;
        int n = node0 + r;
        sX[r][c] = (n < N) ? x[(size_t)node0 * F_IN + k] : 0.f;
    }
    __syncthreads();
    int il = t >> 4, j = t & 15;
    float acc = 0.f;
    const float* xr = sX[il];
#pragma unroll 8
    for (int k = 0; k < F_IN; ++k) acc += xr[k] * sW[k * F_HID + j];
    int n = node0 + il;
    float v = (n < N) ? acc * dinv[n] : 0.f;
    float other = __shfl_xor(v, 1);       // partner channel (j^1), same wave
    if (n < N && !(j & 1)) hs1b[(size_t)n * 8 + (j >> 1)] = pk2(v, other);
}

// bucket aggregation layer 1: gather bf16 rows (8 lanes/edge, 4-way ILP) into
// LDS fp32 acc (stride 17 vs bank conflicts); epilogue fuses self-loop, dinv,
// bias, relu AND the next layer's dinv pre-scale; bf16 output.
__global__ void k_agg1(const u32* __restrict__ hs1b, const u32* __restrict__ pairs,
                       const int* __restrict__ bptr, const float* __restrict__ dinv,
                       const float* __restrict__ b1, u32* __restrict__ h1b, int N) {
    __shared__ float acc[BNODES * 17];
    int t = threadIdx.x;
    for (int k = t; k < BNODES * 17; k += 256) acc[k] = 0.f;
    __syncthreads();
    int b = blockIdx.x;
    int s0 = bptr[b], s1 = bptr[b + 1];
    int g = t >> 3, j8 = t & 7, c0 = j8 * 2;
    int e = s0;
    for (; e + 128 <= s1; e += 128) {
        u32 v0 = pairs[e + g], v1 = pairs[e + 32 + g];
        u32 v2 = pairs[e + 64 + g], v3 = pairs[e + 96 + g];
        u32 d0 = hs1b[(size_t)(v0 & 0x1FFFFu) * 8 + j8];
        u32 d1 = hs1b[(size_t)(v1 & 0x1FFFFu) * 8 + j8];
        u32 d2 = hs1b[(size_t)(v2 & 0x1FFFFu) * 8 + j8];
        u32 d3 = hs1b[(size_t)(v3 & 0x1FFFFu) * 8 + j8];
        int a0 = (v0 >> 17) * 17 + c0, a1 = (v1 >> 17) * 17 + c0;
        int a2 = (v2 >> 17) * 17 + c0, a3 = (v3 >> 17) * 17 + c0;
        atomicAdd(&acc[a0], bflo(d0)); atomicAdd(&acc[a0 + 1], bfhi(d0));
        atomicAdd(&acc[a1], bflo(d1)); atomicAdd(&acc[a1 + 1], bfhi(d1));
        atomicAdd(&acc[a2], bflo(d2)); atomicAdd(&acc[a2 + 1], bfhi(d2));
        atomicAdd(&acc[a3], bflo(d3)); atomicAdd(&acc[a3 + 1], bfhi(d3));
    }
    for (int ee = e + g; ee < s1; ee += 32) {
        u32 v = pairs[ee];
        u32 d = hs1b[(size_t)(v & 0x1FFFFu) * 8 + j8];
        int a = (v >> 17) * 17 + c0;
        atomicAdd(&acc[a], bflo(d)); atomicAdd(&acc[a + 1], bfhi(d));
    }
    __syncthreads();
    int nl = t >> 3, cp = t & 7;              // 32 nodes x 8 ch-pairs = 256
    int n = (b << BSH) + nl;
    if (n < N) {
        u32 sd = hs1b[(size_t)n * 8 + cp];
        float dv = dinv[n];
        float r0 = dv * (acc[nl * 17 + cp * 2]     + bflo(sd)) + b1[cp * 2];
        float r1 = dv * (acc[nl * 17 + cp * 2 + 1] + bfhi(sd)) + b1[cp * 2 + 1];
        r0 = (r0 > 0.f ? r0 : 0.f) * dv;      // pre-scale for layer-2 gather
        r1 = (r1 > 0.f ? r1 : 0.f) * dv;
        h1b[(size_t)n * 8 + cp] = pk2(r0, r1);
    }
}

// bucket aggregation layer 2 + fused 16x32 GEMM (W2) + bias + log_softmax.
__global__ void k_agg2_final(const u32* __restrict__ h1b, const u32* __restrict__ pairs,
                             const int* __restrict__ bptr, const float* __restrict__ dinv,
                             const float* __restrict__ W2, const float* __restrict__ b2,
                             float* __restrict__ out, int N) {
    __shared__ float acc[BNODES * 17];
    __shared__ float sW2[F_HID * F_OUT];
    __shared__ float sb2[F_OUT];
    int t = threadIdx.x;
    for (int k = t; k < BNODES * 17; k += 256) acc[k] = 0.f;
    for (int k = t; k < F_HID * F_OUT; k += 256) sW2[k] = W2[k];
    if (t < F_OUT) sb2[t] = b2[t];
    __syncthreads();
    int b = blockIdx.x;
    int s0 = bptr[b], s1 = bptr[b + 1];
    int g = t >> 3, j8 = t & 7, c0 = j8 * 2;
    int e = s0;
    for (; e + 128 <= s1; e += 128) {
        u32 v0 = pairs[e + g], v1 = pairs[e + 32 + g];
        u32 v2 = pairs[e + 64 + g], v3 = pairs[e + 96 + g];
        u32 d0 = h1b[(size_t)(v0 & 0x1FFFFu) * 8 + j8];
        u32 d1 = h1b[(size_t)(v1 & 0x1FFFFu) * 8 + j8];
        u32 d2 = h1b[(size_t)(v2 & 0x1FFFFu) * 8 + j8];
        u32 d3 = h1b[(size_t)(v3 & 0x1FFFFu) * 8 + j8];
        int a0 = (v0 >> 17) * 17 + c0, a1 = (v1 >> 17) * 17 + c0;
        int a2 = (v2 >> 17) * 17 + c0, a3 = (v3 >> 17) * 17 + c0;
        atomicAdd(&acc[a0], bflo(d0)); atomicAdd(&acc[a0 + 1], bfhi(d0));
        atomicAdd(&acc[a1], bflo(d1)); atomicAdd(&acc[a1 + 1], bfhi(d1));
        atomicAdd(&acc[a2], bflo(d2)); atomicAdd(&acc[a2 + 1], bfhi(d2));
        atomicAdd(&acc[a3], bflo(d3)); atomicAdd(&acc[a3 + 1], bfhi(d3));
    }
    for (int ee = e + g; ee < s1; ee += 32) {
        u32 v = pairs[ee];
        u32 d = h1b[(size_t)(v & 0x1FFFFu) * 8 + j8];
        int a = (v >> 17) * 17 + c0;
        atomicAdd(&acc[a], bflo(d)); atomicAdd(&acc[a + 1], bfhi(d));
    }
    __syncthreads();
    {   // finalize in place: pre = dinv*(acc + self)
        int nl = t >> 3, cp = t & 7;
        int n = (b << BSH) + nl;
        if (n < N) {
            u32 sd = h1b[(size_t)n * 8 + cp];
            float dv = dinv[n];
            acc[nl * 17 + cp * 2]     = dv * (acc[nl * 17 + cp * 2]     + bflo(sd));
            acc[nl * 17 + cp * 2 + 1] = dv * (acc[nl * 17 + cp * 2 + 1] + bfhi(sd));
        }
    }
    __syncthreads();
    // 16x32 GEMM + bias + log_softmax: 8 nodes/round x 32 lanes, 4 rounds
    int g2 = t >> 5, j = t & 31;
    for (int r = 0; r < 4; ++r) {
        int nl = r * 8 + g2;
        int n = (b << BSH) + nl;
        if (n < N) {
            float z = sb2[j];
#pragma unroll
            for (int k = 0; k < F_HID; ++k) z += acc[nl * 17 + k] * sW2[k * F_OUT + j];
            float m = z;
            for (int off = 16; off > 0; off >>= 1) m = fmaxf(m, __shfl_xor(m, off, 32));
            float s = __expf(z - m);
            for (int off = 16; off > 0; off >>= 1) s += __shfl_xor(s, off, 32);
            out[(size_t)n * F_OUT + j] = z - m - __logf(s);
        }
    }
}

extern "C" void kernel_launch(void* const* d_in, const int* in_sizes, int n_in,
                              void* d_out, int out_size, void* d_ws, size_t ws_size,
                              hipStream_t stream) {
    const float* x  = (const float*)d_in[0];
    const int*   ei = (const int*)d_in[1];   // [2, E] int32
    const float* W1 = (const float*)d_in[2];
    const float* b1 = (const float*)d_in[3];
    const float* W2 = (const float*)d_in[4];
    const float* b2 = (const float*)d_in[5];
    float* out = (float*)d_out;

    int N = in_sizes[0] / F_IN;
    int E = in_sizes[1] / 2;
    const int* row = ei;
    const int* col = ei + E;
    int nbk = (N + BNODES - 1) >> BSH;           // 3125
    int nchunk = (E + CEDGE - 1) / CEDGE;        // 782

    // ws: bcnt[MAXBK]i | bptr[MAXBK+1]i | bcur[MAXBK]i | dinv[N]f |
    //     pairs[E]u32 | hs1b[8N]u32 | h1b[8N]u32   (~20 MB)
    char* w = (char*)d_ws;
    int*   bcnt = (int*)w;    w += sizeof(int) * MAXBK;
    int*   bptr = (int*)w;    w += sizeof(int) * (MAXBK + 1);
    int*   bcur = (int*)w;    w += sizeof(int) * MAXBK;
    float* dinv = (float*)w;  w += sizeof(float) * N;
    u32*   pairs = (u32*)w;   w += sizeof(u32) * (size_t)E;
    u32*   hs1b = (u32*)w;    w += sizeof(u32) * (size_t)N * 8;
    u32*   h1b  = (u32*)w;

    k_zero_i<<<(MAXBK + 255) / 256, 256, 0, stream>>>(bcnt, MAXBK);
    k_bucket_cnt<<<nchunk, 256, 0, stream>>>(col, E, bcnt, nbk);
    k_bscan<<<1, 256, 0, stream>>>(bcnt, bptr, bcur, nbk, E);
    k_bin_fill<<<nchunk, 256, 0, stream>>>(row, col, E, bcur, pairs, nbk);
    k_dinv_bucket<<<nbk, 256, 0, stream>>>(pairs, bptr, dinv, N);

    k_gemm1<<<(N + 15) / 16, 256, 0, stream>>>(x, W1, dinv, hs1b, N);
    k_agg1<<<nbk, 256, 0, stream>>>(hs1b, pairs, bptr, dinv, b1, h1b, N);
    k_agg2_final<<<nbk, 256, 0, stream>>>(h1b, pairs, bptr, dinv, W2, b2, out, N);
}

// Round 7
// 307.372 us; speedup vs baseline: 4.0511x; 2.6705x over previous
//
#include <hip/hip_runtime.h>
#include <math.h>

// GCN 2-layer. 32-node buckets; per-bucket in-LDS counting sort of edges by
// target node, then REGISTER accumulation (8 lanes x 2ch per node) — no f32
// LDS atomics (R6: 51.2M ds_add f32 per layer = 293us each, 3.5cyc/atomic).
// bf16 gather sources (3.2MB, L2-resident); W2 commuted past aggregation.
//   hs1 = dinv*(x@W1) [bf16]; h1s = dinv*relu(dinv*(Σ+self)+b1) [bf16]
//   pre = dinv*(Σ h1s + self); out = log_softmax(pre@W2 + b2)
// edge_index: int32 (harness-converted; R2 crash proved 8E-byte buffer).
#define F_IN  128
#define F_HID 16
#define F_OUT 32
#define BSH    5
#define BNODES 32
#define MAXBK  3328        // >= nbk (3125 for N=100k)
#define SCAN_IT 13
#define CEDGE  4096        // edges per binning chunk (256 thr x 16)
#define CAP    1280        // staged edges per bucket (mean 1024, sd 32)

typedef unsigned int u32;

__device__ inline float bflo(u32 d) { return __uint_as_float(d << 16); }
__device__ inline float bfhi(u32 d) { return __uint_as_float(d & 0xFFFF0000u); }
__device__ inline u32 f2bf(float f) {
    u32 u = __float_as_uint(f);
    return (u + 0x7FFFu + ((u >> 16) & 1u)) >> 16;  // RNE
}
__device__ inline u32 pk2(float lo, float hi) { return f2bf(lo) | (f2bf(hi) << 16); }

__global__ void k_zero_i(int* p, int n) {
    int i = blockIdx.x * blockDim.x + threadIdx.x;
    if (i < n) p[i] = 0;
}

// per-chunk LDS histogram of bucket ids -> global bucket counts
__global__ void k_bucket_cnt(const int* __restrict__ col, int E,
                             int* __restrict__ bcnt, int nbk) {
    __shared__ int h[MAXBK];
    int t = threadIdx.x;
    for (int k = t; k < nbk; k += 256) h[k] = 0;
    __syncthreads();
    int e0 = blockIdx.x * CEDGE;
#pragma unroll
    for (int k = 0; k < 16; ++k) {
        int e = e0 + k * 256 + t;
        if (e < E) atomicAdd(&h[col[e] >> BSH], 1);
    }
    __syncthreads();
    for (int k = t; k < nbk; k += 256) if (h[k]) atomicAdd(&bcnt[k], h[k]);
}

// single-block exclusive scan of bcnt[nbk] -> bptr, bcur
__global__ void k_bscan(const int* __restrict__ bcnt, int* __restrict__ bptr,
                        int* __restrict__ bcur, int nbk, int E) {
    __shared__ int sd[256];
    int t = threadIdx.x;
    int base = t * SCAN_IT;
    int v[SCAN_IT], ts = 0;
#pragma unroll
    for (int k = 0; k < SCAN_IT; ++k) {
        v[k] = (base + k < nbk) ? bcnt[base + k] : 0;
        ts += v[k];
    }
    sd[t] = ts;
    __syncthreads();
    for (int off = 1; off < 256; off <<= 1) {
        int x = (t >= off) ? sd[t - off] : 0;
        __syncthreads();
        sd[t] += x;
        __syncthreads();
    }
    int run = sd[t] - ts;
#pragma unroll
    for (int k = 0; k < SCAN_IT; ++k) {
        if (base + k < nbk) { bptr[base + k] = run; bcur[base + k] = run; }
        run += v[k];
    }
    if (t == 0) bptr[nbk] = E;
}

// bin edges by bucket. pack = (col&31)<<17 | row.
__global__ void k_bin_fill(const int* __restrict__ row, const int* __restrict__ col,
                           int E, int* __restrict__ bcur, u32* __restrict__ pairs,
                           int nbk) {
    __shared__ int h[MAXBK];
    __shared__ int bse[MAXBK];
    int t = threadIdx.x;
    for (int k = t; k < nbk; k += 256) h[k] = 0;
    __syncthreads();
    int e0 = blockIdx.x * CEDGE;
    int myb[16], myp[16]; u32 myv[16];
#pragma unroll
    for (int k = 0; k < 16; ++k) {
        int e = e0 + k * 256 + t;
        myb[k] = -1;
        if (e < E) {
            int c = col[e], r = row[e];
            int b = c >> BSH;
            myb[k] = b;
            myp[k] = atomicAdd(&h[b], 1);
            myv[k] = ((u32)(c & (BNODES - 1)) << 17) | (u32)r;
        }
    }
    __syncthreads();
    for (int k = t; k < nbk; k += 256)
        bse[k] = h[k] ? atomicAdd(&bcur[k], h[k]) : 0;
    __syncthreads();
#pragma unroll
    for (int k = 0; k < 16; ++k)
        if (myb[k] >= 0) pairs[bse[myb[k]] + myp[k]] = myv[k];
}

// per-bucket in-degree -> dinv = rsqrt(deg+1)
__global__ void k_dinv_bucket(const u32* __restrict__ pairs, const int* __restrict__ bptr,
                              float* __restrict__ dinv, int N) {
    __shared__ int c[BNODES];
    int b = blockIdx.x, t = threadIdx.x;
    if (t < BNODES) c[t] = 0;
    __syncthreads();
    int s0 = bptr[b], s1 = bptr[b + 1];
    for (int e = s0 + t; e < s1; e += 256) atomicAdd(&c[pairs[e] >> 17], 1);
    __syncthreads();
    int n = (b << BSH) + t;
    if (t < BNODES && n < N) dinv[n] = rsqrtf((float)c[t] + 1.0f);
}

// 16 nodes x 16 ch per block; float4-staged x; bf16-packed hs1 = dinv*(x@W1).
__global__ void k_gemm1(const float* __restrict__ x, const float* __restrict__ W1,
                        const float* __restrict__ dinv, u32* __restrict__ hs1b, int N) {
    __shared__ float sW[F_IN * F_HID];
    __shared__ float sX[16][F_IN + 4];    // row stride 132: 16B-aligned, pad
    int t = threadIdx.x;
    {
        const float4* W4 = (const float4*)W1;
        float4* sW4 = (float4*)sW;
#pragma unroll
        for (int k = t; k < F_IN * F_HID / 4; k += 256) sW4[k] = W4[k];
    }
    int node0 = blockIdx.x * 16;
    {
        const float4* x4 = (const float4*)(x + (size_t)node0 * F_IN);
#pragma unroll
        for (int k = t; k < 16 * F_IN / 4; k += 256) {
            int r = k >> 5, c4 = k & 31;          // 32 float4 per row
            float4 v = (node0 + r < N) ? x4[k] : make_float4(0.f, 0.f, 0.f, 0.f);
            *(float4*)&sX[r][c4 * 4] = v;
        }
    }
    __syncthreads();
    int il = t >> 4, j = t & 15;
    float acc = 0.f;
    const float* xr = sX[il];
#pragma unroll 8
    for (int k = 0; k < F_IN; ++k) acc += xr[k] * sW[k * F_HID + j];
    int n = node0 + il;
    float v = (n < N) ? acc * dinv[n] : 0.f;
    float other = __shfl_xor(v, 1);
    if (n < N && !(j & 1)) hs1b[(size_t)n * 8 + (j >> 1)] = pk2(v, other);
}

// ---- shared agg machinery: counting-sort bucket edges in LDS, then each
// node owned by 8 lanes (2ch each) accumulates its segment in registers. ----
struct AggSort {
    u32* bufA; u32* bufB; int* cnt; int* off; int* cur;
};

__device__ inline void agg_sort(const u32* __restrict__ pairs, int s0, int s1,
                                AggSort s, int t) {
    for (int k = t; k < BNODES; k += 256) { s.cnt[k] = 0; }
    __syncthreads();
    int m = s1 - s0; if (m > CAP) m = CAP;
    for (int e = t; e < m; e += 256) {
        u32 v = pairs[s0 + e];
        s.bufA[e] = v;
        atomicAdd(&s.cnt[v >> 17], 1);
    }
    __syncthreads();
    if (t == 0) {
        int run = 0;
#pragma unroll
        for (int i = 0; i < BNODES; ++i) { s.off[i] = run; s.cur[i] = run; run += s.cnt[i]; }
        s.off[BNODES] = run;
    }
    __syncthreads();
    for (int e = t; e < m; e += 256) {
        u32 v = s.bufA[e];
        int r = atomicAdd(&s.cur[v >> 17], 1);
        s.bufB[r] = v & 0x1FFFFu;
    }
    __syncthreads();
}

// accumulate 2 channels (j8) of node-local g over its sorted segment + overflow
__device__ inline void agg_accum(const u32* __restrict__ src, const u32* __restrict__ pairs,
                                 int s0, int s1, const AggSort& s, int g, int j8,
                                 float& A0, float& A1) {
    float a0 = 0.f, a1 = 0.f, b0 = 0.f, b1v = 0.f;
    int beg = s.off[g], end = s.off[g + 1];
    int e = beg;
    for (; e + 2 <= end; e += 2) {
        u32 i0 = s.bufB[e], i1 = s.bufB[e + 1];
        u32 d0 = src[(size_t)i0 * 8 + j8];
        u32 d1 = src[(size_t)i1 * 8 + j8];
        a0 += bflo(d0); a1 += bfhi(d0);
        b0 += bflo(d1); b1v += bfhi(d1);
    }
    if (e < end) {
        u32 d = src[(size_t)s.bufB[e] * 8 + j8];
        a0 += bflo(d); a1 += bfhi(d);
    }
    // overflow tail (normally zero-trip): scan global pairs, match node id
    for (int ee = s0 + CAP; ee < s1; ++ee) {
        u32 v = pairs[ee];
        if ((int)(v >> 17) == g) {
            u32 d = src[(size_t)(v & 0x1FFFFu) * 8 + j8];
            a0 += bflo(d); a1 += bfhi(d);
        }
    }
    A0 = a0 + b0; A1 = a1 + b1v;
}

// layer-1 aggregation: register acc + fused self/dinv/bias/relu/pre-scale.
__global__ void k_agg1(const u32* __restrict__ hs1b, const u32* __restrict__ pairs,
                       const int* __restrict__ bptr, const float* __restrict__ dinv,
                       const float* __restrict__ b1, u32* __restrict__ h1b, int N) {
    __shared__ u32 bufA[CAP];
    __shared__ u32 bufB[CAP];
    __shared__ int cnt[BNODES], off[BNODES + 1], cur[BNODES];
    AggSort s { bufA, bufB, cnt, off, cur };
    int t = threadIdx.x;
    int b = blockIdx.x;
    int s0 = bptr[b], s1 = bptr[b + 1];
    agg_sort(pairs, s0, s1, s, t);
    int g = t >> 3, j8 = t & 7;
    float A0, A1;
    agg_accum(hs1b, pairs, s0, s1, s, g, j8, A0, A1);
    int n = (b << BSH) + g;
    if (n < N) {
        u32 sd = hs1b[(size_t)n * 8 + j8];
        float dv = dinv[n];
        float r0 = dv * (A0 + bflo(sd)) + b1[j8 * 2];
        float r1 = dv * (A1 + bfhi(sd)) + b1[j8 * 2 + 1];
        r0 = (r0 > 0.f ? r0 : 0.f) * dv;   // pre-scale for layer-2 gather
        r1 = (r1 > 0.f ? r1 : 0.f) * dv;
        h1b[(size_t)n * 8 + j8] = pk2(r0, r1);
    }
}

// layer-2 aggregation + fused 16x32 GEMM (W2) + bias + log_softmax.
__global__ void k_agg2_final(const u32* __restrict__ h1b, const u32* __restrict__ pairs,
                             const int* __restrict__ bptr, const float* __restrict__ dinv,
                             const float* __restrict__ W2, const float* __restrict__ b2,
                             float* __restrict__ out, int N) {
    __shared__ u32 bufA[CAP];
    __shared__ u32 bufB[CAP];
    __shared__ int cnt[BNODES], off[BNODES + 1], cur[BNODES];
    __shared__ float accS[BNODES * 17];
    __shared__ float sW2[F_HID * F_OUT];
    __shared__ float sb2[F_OUT];
    AggSort s { bufA, bufB, cnt, off, cur };
    int t = threadIdx.x;
    for (int k = t; k < F_HID * F_OUT; k += 256) sW2[k] = W2[k];
    if (t < F_OUT) sb2[t] = b2[t];
    int b = blockIdx.x;
    int s0 = bptr[b], s1 = bptr[b + 1];
    agg_sort(pairs, s0, s1, s, t);
    int g = t >> 3, j8 = t & 7;
    float A0, A1;
    agg_accum(h1b, pairs, s0, s1, s, g, j8, A0, A1);
    int n = (b << BSH) + g;
    if (n < N) {
        u32 sd = h1b[(size_t)n * 8 + j8];
        float dv = dinv[n];
        accS[g * 17 + j8 * 2]     = dv * (A0 + bflo(sd));
        accS[g * 17 + j8 * 2 + 1] = dv * (A1 + bfhi(sd));
    }
    __syncthreads();
    // 16x32 GEMM + bias + log_softmax: 8 nodes/round x 32 lanes, 4 rounds
    int g2 = t >> 5, j = t & 31;
    for (int r = 0; r < 4; ++r) {
        int nl = r * 8 + g2;
        int n2 = (b << BSH) + nl;
        if (n2 < N) {
            float z = sb2[j];
#pragma unroll
            for (int k = 0; k < F_HID; ++k) z += accS[nl * 17 + k] * sW2[k * F_OUT + j];
            float m = z;
            for (int off2 = 16; off2 > 0; off2 >>= 1) m = fmaxf(m, __shfl_xor(m, off2, 32));
            float ssum = __expf(z - m);
            for (int off2 = 16; off2 > 0; off2 >>= 1) ssum += __shfl_xor(ssum, off2, 32);
            out[(size_t)n2 * F_OUT + j] = z - m - __logf(ssum);
        }
    }
}

extern "C" void kernel_launch(void* const* d_in, const int* in_sizes, int n_in,
                              void* d_out, int out_size, void* d_ws, size_t ws_size,
                              hipStream_t stream) {
    const float* x  = (const float*)d_in[0];
    const int*   ei = (const int*)d_in[1];   // [2, E] int32
    const float* W1 = (const float*)d_in[2];
    const float* b1 = (const float*)d_in[3];
    const float* W2 = (const float*)d_in[4];
    const float* b2 = (const float*)d_in[5];
    float* out = (float*)d_out;

    int N = in_sizes[0] / F_IN;
    int E = in_sizes[1] / 2;
    const int* row = ei;
    const int* col = ei + E;
    int nbk = (N + BNODES - 1) >> BSH;           // 3125
    int nchunk = (E + CEDGE - 1) / CEDGE;        // 782

    // ws: bcnt | bptr | bcur | dinv[N] | pairs[E] | hs1b[8N] | h1b[8N]  (~20MB)
    char* w = (char*)d_ws;
    int*   bcnt = (int*)w;    w += sizeof(int) * MAXBK;
    int*   bptr = (int*)w;    w += sizeof(int) * (MAXBK + 1);
    int*   bcur = (int*)w;    w += sizeof(int) * MAXBK;
    float* dinv = (float*)w;  w += sizeof(float) * N;
    u32*   pairs = (u32*)w;   w += sizeof(u32) * (size_t)E;
    u32*   hs1b = (u32*)w;    w += sizeof(u32) * (size_t)N * 8;
    u32*   h1b  = (u32*)w;

    k_zero_i<<<(MAXBK + 255) / 256, 256, 0, stream>>>(bcnt, MAXBK);
    k_bucket_cnt<<<nchunk, 256, 0, stream>>>(col, E, bcnt, nbk);
    k_bscan<<<1, 256, 0, stream>>>(bcnt, bptr, bcur, nbk, E);
    k_bin_fill<<<nchunk, 256, 0, stream>>>(row, col, E, bcur, pairs, nbk);
    k_dinv_bucket<<<nbk, 256, 0, stream>>>(pairs, bptr, dinv, N);

    k_gemm1<<<(N + 15) / 16, 256, 0, stream>>>(x, W1, dinv, hs1b, N);
    k_agg1<<<nbk, 256, 0, stream>>>(hs1b, pairs, bptr, dinv, b1, h1b, N);
    k_agg2_final<<<nbk, 256, 0, stream>>>(h1b, pairs, bptr, dinv, W2, b2, out, N);
}